// Round 1
// baseline (3332.326 us; speedup 1.0000x reference)
//
#include <hip/hip_runtime.h>

#define H 10
#define W 11
#define HP 12   // padded rows
#define WP 13   // padded cols
#define C1 16
#define C2 32
#define PIX 110
#define K3 3520
#define NFC 256
#define NSEQ 2048
#define WINLEN 10
#define HID 64
#define NCLS 7
#define NFRAMES 20480
#define CHUNK 4096

__device__ __forceinline__ float clip01(float x){ return fminf(fmaxf(x, 0.f), 1.f); }
__device__ __forceinline__ float clip11(float x){ return fminf(fmaxf(x, -1.f), 1.f); }

// ---------------------------------------------------------------------------
// Kernel 1: per-frame jitter + conv1 + ScaleReLU + conv2 + ScaleReLU
// One block (256 threads) per frame. Padded LDS tiles -> branch-free 3x3.
// ---------------------------------------------------------------------------
__global__ __launch_bounds__(256)
void conv_fused(const float* __restrict__ input, const float* __restrict__ noise,
                const float* __restrict__ w1, const float* __restrict__ w2,
                float* __restrict__ a2, int frame0)
{
    __shared__ float xinp[HP * WP];         // padded jittered input (1 ch)
    __shared__ float a1p[C1][HP * WP];      // padded conv1 output
    __shared__ float s_w1[C1 * 9];
    __shared__ float s_w2[C2 * C1 * 9];

    const int tid = threadIdx.x;
    const int frame = frame0 + blockIdx.x;

    for (int i = tid; i < C1 * 9; i += 256) s_w1[i] = w1[i];
    for (int i = tid; i < C2 * C1 * 9; i += 256) s_w2[i] = w2[i];
    for (int i = tid; i < HP * WP; i += 256) xinp[i] = 0.f;
    for (int i = tid; i < C1 * HP * WP; i += 256) (&a1p[0][0])[i] = 0.f;
    __syncthreads();

    const float* in_row = input + (size_t)frame * PIX;
    const float* nz_row = noise + (size_t)frame * PIX;
    for (int p = tid; p < PIX; p += 256) {
        int i = p / W, j = p % W;
        xinp[(i + 1) * WP + (j + 1)] = in_row[p] * (1.f + nz_row[p] / 20.f);
    }
    __syncthreads();

    // conv1: 16 x 110 outputs, 9 MACs each
    for (int idx = tid; idx < C1 * PIX; idx += 256) {
        int c = idx / PIX, p = idx % PIX;
        int i = p / W, j = p % W;
        const float* wr = &s_w1[c * 9];
        const float* xp = &xinp[i * WP + j];
        float acc = xp[0]*wr[0] + xp[1]*wr[1] + xp[2]*wr[2]
                  + xp[WP]*wr[3] + xp[WP+1]*wr[4] + xp[WP+2]*wr[5]
                  + xp[2*WP]*wr[6] + xp[2*WP+1]*wr[7] + xp[2*WP+2]*wr[8];
        a1p[c][(i + 1) * WP + (j + 1)] = clip01(acc);
    }
    __syncthreads();

    // conv2: 32 x 110 outputs, 144 MACs each; write NCHW-flat row (3520)
    float* a2row = a2 + (size_t)blockIdx.x * K3;
    for (int idx = tid; idx < C2 * PIX; idx += 256) {
        int c = idx / PIX, p = idx % PIX;
        int i = p / W, j = p % W;
        float acc = 0.f;
        #pragma unroll
        for (int ci = 0; ci < C1; ++ci) {
            const float* wr = &s_w2[(c * C1 + ci) * 9];
            const float* xp = &a1p[ci][i * WP + j];
            acc += xp[0]*wr[0] + xp[1]*wr[1] + xp[2]*wr[2]
                 + xp[WP]*wr[3] + xp[WP+1]*wr[4] + xp[WP+2]*wr[5]
                 + xp[2*WP]*wr[6] + xp[2*WP+1]*wr[7] + xp[2*WP+2]*wr[8];
        }
        a2row[idx] = clip01(acc);
    }
}

// ---------------------------------------------------------------------------
// Kernel 0: transpose w3 (256 x 3520) -> w3t (3520 x 256) for coalesced GEMM B
// ---------------------------------------------------------------------------
__global__ __launch_bounds__(256)
void transpose_w3(const float* __restrict__ w3, float* __restrict__ w3t)
{
    int idx = blockIdx.x * 256 + threadIdx.x;
    if (idx < NFC * K3) {
        int n = idx / K3, k = idx % K3;
        w3t[(size_t)k * NFC + n] = w3[idx];
    }
}

// ---------------------------------------------------------------------------
// Kernel 2: fc3 GEMM: xs[frame0+m][n] = clip01( sum_k a2[m][k] * w3t[k][n] )
// 64x64 block tile, 4x4 per thread, BK=16.
// ---------------------------------------------------------------------------
__global__ __launch_bounds__(256)
void gemm_fc3(const float* __restrict__ A, const float* __restrict__ Bt,
              float* __restrict__ xs, int frame0)
{
    __shared__ float As[16][64 + 1];
    __shared__ float Bs[16][64];
    const int tid = threadIdx.x;
    const int bm = blockIdx.x * 64;
    const int bn = blockIdx.y * 64;
    const int tx = tid & 15, ty = tid >> 4;
    float acc[4][4] = {};

    for (int k0 = 0; k0 < K3; k0 += 16) {
        #pragma unroll
        for (int r = 0; r < 4; ++r) {
            int i = tid + 256 * r;          // 0..1023
            int m = i >> 4, kk = i & 15;
            As[kk][m] = A[(size_t)(bm + m) * K3 + k0 + kk];
            int kb = i >> 6, nb = i & 63;
            Bs[kb][nb] = Bt[(size_t)(k0 + kb) * NFC + bn + nb];
        }
        __syncthreads();
        #pragma unroll
        for (int kk = 0; kk < 16; ++kk) {
            float a[4], b[4];
            #pragma unroll
            for (int i = 0; i < 4; ++i) a[i] = As[kk][ty * 4 + i];
            #pragma unroll
            for (int j = 0; j < 4; ++j) b[j] = Bs[kk][tx * 4 + j];
            #pragma unroll
            for (int i = 0; i < 4; ++i)
                #pragma unroll
                for (int j = 0; j < 4; ++j)
                    acc[i][j] += a[i] * b[j];
        }
        __syncthreads();
    }

    #pragma unroll
    for (int i = 0; i < 4; ++i) {
        int row = frame0 + bm + ty * 4 + i;
        #pragma unroll
        for (int j = 0; j < 4; ++j)
            xs[(size_t)row * NFC + bn + tx * 4 + j] = clip01(acc[i][j]);
    }
}

// ---------------------------------------------------------------------------
// Kernel 3: MGU recurrence (10 steps) + fc5, one 64-thread block per sequence
// ---------------------------------------------------------------------------
__global__ __launch_bounds__(64)
void mgu_kernel(const float* __restrict__ xs, const float* __restrict__ wf,
                const float* __restrict__ wn, const float* __restrict__ w5,
                float* __restrict__ out)
{
    const int s = blockIdx.x;
    const int j = threadIdx.x;   // 0..63 = hidden unit
    __shared__ float xt[NFC];
    __shared__ float h[HID];
    __shared__ float fh[HID];

    h[j] = 0.f;
    float hj = 0.f;

    for (int t = 0; t < WINLEN; ++t) {
        const float* xrow = xs + ((size_t)s * WINLEN + t) * NFC;
        for (int i = j; i < NFC; i += HID) xt[i] = xrow[i];
        __syncthreads();   // xt ready; prev-iter h store visible

        // f = clip( wf . [xt, h] / 6 + 0.5 )
        const float* wfr = wf + j * (NFC + HID);
        float af = 0.f;
        #pragma unroll 4
        for (int k = 0; k < NFC; ++k) af += wfr[k] * xt[k];
        #pragma unroll 4
        for (int k = 0; k < HID; ++k) af += wfr[NFC + k] * h[k];
        float f = clip01(af / 6.f + 0.5f);
        fh[j] = f * h[j];
        __syncthreads();   // fh ready; all h reads of this iter done

        // n = clip( wn . [xt, f*h] , -1, 1 )
        const float* wnr = wn + j * (NFC + HID);
        float an = 0.f;
        #pragma unroll 4
        for (int k = 0; k < NFC; ++k) an += wnr[k] * xt[k];
        #pragma unroll 4
        for (int k = 0; k < HID; ++k) an += wnr[NFC + k] * fh[k];
        float n = clip11(an);
        hj = (1.f - f) * h[j] + f * n;
        __syncthreads();   // xt/fh reads done before overwrite
        h[j] = hj;
    }
    __syncthreads();

    if (j < NCLS) {
        const float* w5r = w5 + j * HID;
        float acc = 0.f;
        #pragma unroll
        for (int k = 0; k < HID; ++k) acc += w5r[k] * h[k];
        out[(size_t)s * NCLS + j] = clip11(acc);
    }
}

// ---------------------------------------------------------------------------
extern "C" void kernel_launch(void* const* d_in, const int* in_sizes, int n_in,
                              void* d_out, int out_size, void* d_ws, size_t ws_size,
                              hipStream_t stream)
{
    const float* input = (const float*)d_in[0];
    const float* noise = (const float*)d_in[1];
    const float* w1    = (const float*)d_in[2];
    const float* w2    = (const float*)d_in[3];
    const float* w3    = (const float*)d_in[4];
    const float* wf    = (const float*)d_in[5];
    const float* wn    = (const float*)d_in[6];
    const float* w5    = (const float*)d_in[7];
    float* out = (float*)d_out;

    float* w3t = (float*)d_ws;                        // 3520*256      = 901,120 f
    float* xs  = w3t + (size_t)K3 * NFC;              // 20480*256     = 5,242,880 f
    float* a2  = xs  + (size_t)NFRAMES * NFC;         // CHUNK*3520    = 14,417,920 f
    // total ~78.5 MB of ws

    transpose_w3<<<(NFC * K3 + 255) / 256, 256, 0, stream>>>(w3, w3t);

    for (int f0 = 0; f0 < NFRAMES; f0 += CHUNK) {
        conv_fused<<<CHUNK, 256, 0, stream>>>(input, noise, w1, w2, a2, f0);
        gemm_fc3<<<dim3(CHUNK / 64, NFC / 64), 256, 0, stream>>>(a2, w3t, xs, f0);
    }

    mgu_kernel<<<NSEQ, 64, 0, stream>>>(xs, wf, wn, w5, out);
}

// Round 5
// 1127.260 us; speedup vs baseline: 2.9561x; 2.9561x over previous
//
#include <hip/hip_runtime.h>

#define H 10
#define W 11
#define HP 12
#define WP 13
#define C1 16
#define C2 32
#define PIX 110
#define K3 3520
#define NFC 256
#define NSEQ 2048
#define WINLEN 10
#define HID 64
#define NCLS 7
#define NFRAMES 20480
#define CHUNK 4096
#define LDP 40   // LDS row pitch (bf16 elems) for GEMM tiles

typedef __attribute__((ext_vector_type(8))) short bf16x8;
typedef __attribute__((ext_vector_type(4))) float f32x4;

__device__ __forceinline__ float clip01(float x){ return fminf(fmaxf(x, 0.f), 1.f); }
__device__ __forceinline__ float clip11(float x){ return fminf(fmaxf(x, -1.f), 1.f); }

__device__ __forceinline__ unsigned short f2bf(float x) {
    union { float f; unsigned u; } v; v.f = x;
    unsigned r = v.u + 0x7FFFu + ((v.u >> 16) & 1u);
    return (unsigned short)(r >> 16);
}
__device__ __forceinline__ float bf2f(unsigned short b) {
    union { unsigned u; float f; } v; v.u = ((unsigned)b) << 16;
    return v.f;
}

// ---------------------------------------------------------------------------
// Prep: w3 (256x3520 fp32) -> hi/lo bf16 ([n][k] layout = MFMA B-fragment order)
// ---------------------------------------------------------------------------
__global__ __launch_bounds__(256)
void prep_w3(const float* __restrict__ w3, unsigned short* __restrict__ hi,
             unsigned short* __restrict__ lo)
{
    int i = blockIdx.x * 256 + threadIdx.x;
    if (i < NFC * K3) {
        float x = w3[i];
        unsigned short h = f2bf(x);
        hi[i] = h;
        lo[i] = f2bf(x - bf2f(h));
    }
}

// Prep: wf/wn (64x320) -> [80][64] float4 chunks: wT[((k/4)*64 + j)*4 + k%4]
__global__ __launch_bounds__(256)
void prep_wT(const float* __restrict__ wf, const float* __restrict__ wn,
             float* __restrict__ wfT, float* __restrict__ wnT)
{
    int i = blockIdx.x * 256 + threadIdx.x;
    if (i < HID * (NFC + HID)) {
        int j = i / (NFC + HID), k = i - j * (NFC + HID);
        int dst = ((k >> 2) * HID + j) * 4 + (k & 3);
        wfT[dst] = wf[i];
        wnT[dst] = wn[i];
    }
}

// ---------------------------------------------------------------------------
// Kernel 1: jitter + conv1 + clip + conv2 + clip. One 320-thread block/frame.
// Epilogue stores a2 as hi/lo bf16 planes (split done ONCE per element here,
// so the GEMM staging is pure vector copies).
// ---------------------------------------------------------------------------
__global__ __launch_bounds__(320)
void conv_fused(const float* __restrict__ input, const float* __restrict__ noise,
                const float* __restrict__ gw1, const float* __restrict__ gw2,
                unsigned short* __restrict__ a2h, unsigned short* __restrict__ a2l,
                int frame0)
{
    __shared__ float xinp[HP * WP];
    __shared__ float a1p[C1][HP * WP];
    __shared__ float s_w1[C1 * 9];
    __shared__ float s_w2p[C2 * 145];   // 144 weights + 1 pad per c2

    const int tid = threadIdx.x;
    const int frame = frame0 + blockIdx.x;

    for (int i = tid; i < C1 * 9; i += 320) s_w1[i] = gw1[i];
    for (int i = tid; i < C2 * 144; i += 320) {
        int c2 = i / 144, r = i - c2 * 144;
        s_w2p[c2 * 145 + r] = gw2[i];
    }
    for (int i = tid; i < HP * WP; i += 320) xinp[i] = 0.f;
    for (int i = tid; i < C1 * HP * WP; i += 320) (&a1p[0][0])[i] = 0.f;
    __syncthreads();

    if (tid < PIX) {
        int i = tid / W, j = tid - i * W;
        xinp[(i + 1) * WP + (j + 1)] =
            input[(size_t)frame * PIX + tid] * (1.f + noise[(size_t)frame * PIX + tid] / 20.f);
    }
    __syncthreads();

    // conv1: 16x110 outputs
    for (int idx = tid; idx < C1 * PIX; idx += 320) {
        int c = idx / PIX, p = idx - c * PIX;
        int i = p / W, j = p - i * W;
        const float* wr = &s_w1[c * 9];
        const float* xp = &xinp[i * WP + j];
        float acc = xp[0]*wr[0] + xp[1]*wr[1] + xp[2]*wr[2]
                  + xp[WP]*wr[3] + xp[WP+1]*wr[4] + xp[WP+2]*wr[5]
                  + xp[2*WP]*wr[6] + xp[2*WP+1]*wr[7] + xp[2*WP+2]*wr[8];
        a1p[c][(i + 1) * WP + (j + 1)] = clip01(acc);
    }
    __syncthreads();

    // conv2: item = (c2, row i); 11 outputs along j per item
    {
        const int c2 = tid & 31;
        const int i  = tid >> 5;   // 0..9
        float acc[W];
        #pragma unroll
        for (int j = 0; j < W; ++j) acc[j] = 0.f;
        const float* wbase = &s_w2p[c2 * 145];
        for (int ci = 0; ci < C1; ++ci) {
            const float* wp = wbase + ci * 9;
            float ww0 = wp[0], ww1 = wp[1], ww2 = wp[2];
            float ww3 = wp[3], ww4 = wp[4], ww5 = wp[5];
            float ww6 = wp[6], ww7 = wp[7], ww8 = wp[8];
            const float* x0 = &a1p[ci][i * WP];
            const float* x1 = x0 + WP;
            const float* x2 = x1 + WP;
            #pragma unroll
            for (int j = 0; j < W; ++j) {
                acc[j] += x0[j]*ww0 + x0[j+1]*ww1 + x0[j+2]*ww2
                        + x1[j]*ww3 + x1[j+1]*ww4 + x1[j+2]*ww5
                        + x2[j]*ww6 + x2[j+1]*ww7 + x2[j+2]*ww8;
            }
        }
        size_t base = (size_t)blockIdx.x * K3 + c2 * PIX + i * W;
        #pragma unroll
        for (int j = 0; j < W; ++j) {
            float v = clip01(acc[j]);
            unsigned short hh = f2bf(v);
            a2h[base + j] = hh;
            a2l[base + j] = f2bf(v - bf2f(hh));
        }
    }
}

// ---------------------------------------------------------------------------
// Kernel 2: fc3 via bf16x3 split MFMA. C = clip01(A @ B^T).
// A, B both pre-split hi/lo bf16 in [row][k] layout. Tile 64x64, 128 threads
// (2 waves), each wave 32 rows x 64 cols = 2x4 16x16 frags. BK=32.
// ONE mfma_f32_16x16x32 per (frag, k-tile): lane covers k=(lane>>4)*8..+7,
// fragment spans the full K=32.
// x*w ~= xh*wh + xh*wl + xl*wh
// ---------------------------------------------------------------------------
__global__ __launch_bounds__(128)
void gemm_fc3(const unsigned short* __restrict__ Ah, const unsigned short* __restrict__ Al,
              const unsigned short* __restrict__ Bh, const unsigned short* __restrict__ Bl,
              float* __restrict__ xs, int frame0)
{
    __shared__ unsigned short As_hi[64 * LDP];
    __shared__ unsigned short As_lo[64 * LDP];
    __shared__ unsigned short Bs_hi[64 * LDP];
    __shared__ unsigned short Bs_lo[64 * LDP];

    const int tid  = threadIdx.x;
    const int lane = tid & 63;
    const int wv   = tid >> 6;            // wave 0..1
    const int bm   = blockIdx.x * 64;     // chunk-local row
    const int bn   = blockIdx.y * 64;
    const int lr   = lane & 15;
    const int ko   = (lane >> 4) * 8;     // k-offset of this lane's 8 elems

    f32x4 acc[2][4];
    #pragma unroll
    for (int mi = 0; mi < 2; ++mi)
        #pragma unroll
        for (int ni = 0; ni < 4; ++ni) {
            f32x4 z = {0.f, 0.f, 0.f, 0.f};
            acc[mi][ni] = z;
        }

    const int rrow = tid >> 1;            // 0..63 (tile row for staging)
    const int rkk  = (tid & 1) * 16;      // k sub-offset (16 shorts)

    for (int k0 = 0; k0 < K3; k0 += 32) {
        size_t ga = (size_t)(bm + rrow) * K3 + k0 + rkk;
        size_t gb = (size_t)(bn + rrow) * K3 + k0 + rkk;
        *(uint4*)&As_hi[rrow * LDP + rkk]     = *(const uint4*)(Ah + ga);
        *(uint4*)&As_hi[rrow * LDP + rkk + 8] = *(const uint4*)(Ah + ga + 8);
        *(uint4*)&As_lo[rrow * LDP + rkk]     = *(const uint4*)(Al + ga);
        *(uint4*)&As_lo[rrow * LDP + rkk + 8] = *(const uint4*)(Al + ga + 8);
        *(uint4*)&Bs_hi[rrow * LDP + rkk]     = *(const uint4*)(Bh + gb);
        *(uint4*)&Bs_hi[rrow * LDP + rkk + 8] = *(const uint4*)(Bh + gb + 8);
        *(uint4*)&Bs_lo[rrow * LDP + rkk]     = *(const uint4*)(Bl + gb);
        *(uint4*)&Bs_lo[rrow * LDP + rkk + 8] = *(const uint4*)(Bl + gb + 8);
        __syncthreads();

        bf16x8 ah[2], al2[2], bh[4], bl[4];
        #pragma unroll
        for (int mi = 0; mi < 2; ++mi) {
            int row = wv * 32 + mi * 16 + lr;
            ah[mi]  = *(const bf16x8*)&As_hi[row * LDP + ko];
            al2[mi] = *(const bf16x8*)&As_lo[row * LDP + ko];
        }
        #pragma unroll
        for (int ni = 0; ni < 4; ++ni) {
            int row = ni * 16 + lr;
            bh[ni] = *(const bf16x8*)&Bs_hi[row * LDP + ko];
            bl[ni] = *(const bf16x8*)&Bs_lo[row * LDP + ko];
        }
        #pragma unroll
        for (int mi = 0; mi < 2; ++mi)
            #pragma unroll
            for (int ni = 0; ni < 4; ++ni) {
                acc[mi][ni] = __builtin_amdgcn_mfma_f32_16x16x32_bf16(ah[mi],  bh[ni], acc[mi][ni], 0, 0, 0);
                acc[mi][ni] = __builtin_amdgcn_mfma_f32_16x16x32_bf16(ah[mi],  bl[ni], acc[mi][ni], 0, 0, 0);
                acc[mi][ni] = __builtin_amdgcn_mfma_f32_16x16x32_bf16(al2[mi], bh[ni], acc[mi][ni], 0, 0, 0);
            }
        __syncthreads();
    }

    // epilogue: C/D layout col = lane&15, row = (lane>>4)*4 + r
    #pragma unroll
    for (int mi = 0; mi < 2; ++mi) {
        int row0 = frame0 + bm + wv * 32 + mi * 16 + (lane >> 4) * 4;
        #pragma unroll
        for (int ni = 0; ni < 4; ++ni) {
            int col = bn + ni * 16 + lr;
            #pragma unroll
            for (int r = 0; r < 4; ++r)
                xs[(size_t)(row0 + r) * NFC + col] = clip01(acc[mi][ni][r]);
        }
    }
}

// ---------------------------------------------------------------------------
// Kernel 3: MGU, 16 sequences per 256-thread block. Thread (sg, j) handles
// hidden unit j for 4 sequences. Weights via pre-transposed coalesced float4.
// ---------------------------------------------------------------------------
__global__ __launch_bounds__(256)
void mgu_kernel(const float* __restrict__ xs, const float* __restrict__ wfT,
                const float* __restrict__ wnT, const float* __restrict__ w5,
                float* __restrict__ out)
{
    __shared__ float xt[16][NFC];
    __shared__ float hs[16][HID];
    __shared__ float fhs[16][HID];

    const int tid = threadIdx.x;
    const int j   = tid & 63;
    const int sg  = tid >> 6;        // 0..3 (4 seqs each)
    const int s0  = blockIdx.x * 16;

    float hreg[4] = {0.f, 0.f, 0.f, 0.f};
    for (int i = tid; i < 16 * HID; i += 256) (&hs[0][0])[i] = 0.f;

    for (int t = 0; t < WINLEN; ++t) {
        {
            const int s = tid >> 4, off = (tid & 15) * 16;
            const float4* src = (const float4*)(xs + ((size_t)(s0 + s) * WINLEN + t) * NFC + off);
            float4* dst = (float4*)&xt[s][off];
            #pragma unroll
            for (int q = 0; q < 4; ++q) dst[q] = src[q];
        }
        __syncthreads();

        // f gate
        float af[4] = {0.f, 0.f, 0.f, 0.f};
        #pragma unroll 4
        for (int kc = 0; kc < 64; ++kc) {
            float4 wvv = *(const float4*)&wfT[(size_t)(kc * HID + j) * 4];
            #pragma unroll
            for (int i2 = 0; i2 < 4; ++i2) {
                float4 xv = *(const float4*)&xt[sg * 4 + i2][kc * 4];
                af[i2] += wvv.x*xv.x + wvv.y*xv.y + wvv.z*xv.z + wvv.w*xv.w;
            }
        }
        #pragma unroll 4
        for (int kc = 0; kc < 16; ++kc) {
            float4 wvv = *(const float4*)&wfT[(size_t)((64 + kc) * HID + j) * 4];
            #pragma unroll
            for (int i2 = 0; i2 < 4; ++i2) {
                float4 hv = *(const float4*)&hs[sg * 4 + i2][kc * 4];
                af[i2] += wvv.x*hv.x + wvv.y*hv.y + wvv.z*hv.z + wvv.w*hv.w;
            }
        }
        float fv[4];
        #pragma unroll
        for (int i2 = 0; i2 < 4; ++i2) {
            fv[i2] = clip01(af[i2] * (1.f / 6.f) + 0.5f);
            fhs[sg * 4 + i2][j] = fv[i2] * hreg[i2];
        }
        __syncthreads();

        // n gate
        float an[4] = {0.f, 0.f, 0.f, 0.f};
        #pragma unroll 4
        for (int kc = 0; kc < 64; ++kc) {
            float4 wvv = *(const float4*)&wnT[(size_t)(kc * HID + j) * 4];
            #pragma unroll
            for (int i2 = 0; i2 < 4; ++i2) {
                float4 xv = *(const float4*)&xt[sg * 4 + i2][kc * 4];
                an[i2] += wvv.x*xv.x + wvv.y*xv.y + wvv.z*xv.z + wvv.w*xv.w;
            }
        }
        #pragma unroll 4
        for (int kc = 0; kc < 16; ++kc) {
            float4 wvv = *(const float4*)&wnT[(size_t)((64 + kc) * HID + j) * 4];
            #pragma unroll
            for (int i2 = 0; i2 < 4; ++i2) {
                float4 hv = *(const float4*)&fhs[sg * 4 + i2][kc * 4];
                an[i2] += wvv.x*hv.x + wvv.y*hv.y + wvv.z*hv.z + wvv.w*hv.w;
            }
        }
        #pragma unroll
        for (int i2 = 0; i2 < 4; ++i2) {
            float nv = clip11(an[i2]);
            hreg[i2] = (1.f - fv[i2]) * hreg[i2] + fv[i2] * nv;
            hs[sg * 4 + i2][j] = hreg[i2];
        }
        __syncthreads();
    }

    if (tid < 16 * NCLS) {
        int s = tid / NCLS, c = tid - s * NCLS;
        float a = 0.f;
        for (int k = 0; k < HID; ++k) a += hs[s][k] * w5[c * HID + k];
        out[(size_t)(s0 + s) * NCLS + c] = clip11(a);
    }
}

// ---------------------------------------------------------------------------
extern "C" void kernel_launch(void* const* d_in, const int* in_sizes, int n_in,
                              void* d_out, int out_size, void* d_ws, size_t ws_size,
                              hipStream_t stream)
{
    const float* input = (const float*)d_in[0];
    const float* noise = (const float*)d_in[1];
    const float* w1    = (const float*)d_in[2];
    const float* w2    = (const float*)d_in[3];
    const float* w3    = (const float*)d_in[4];
    const float* wf    = (const float*)d_in[5];
    const float* wn    = (const float*)d_in[6];
    const float* w5    = (const float*)d_in[7];
    float* out = (float*)d_out;

    // ws layout
    unsigned short* w3_hi = (unsigned short*)d_ws;               // 901120 bf16
    unsigned short* w3_lo = w3_hi + (size_t)NFC * K3;            // 901120 bf16
    float* wfT = (float*)(w3_lo + (size_t)NFC * K3);             // 81920 f
    float* wnT = wfT + (size_t)HID * (NFC + HID);                // 81920 f
    float* xs  = wnT + (size_t)HID * (NFC + HID);                // 20480*256 f
    unsigned short* a2h = (unsigned short*)(xs + (size_t)NFRAMES * NFC); // CHUNK*3520 bf16
    unsigned short* a2l = a2h + (size_t)CHUNK * K3;                      // CHUNK*3520 bf16
    // total ~83 MB

    prep_w3<<<(NFC * K3 + 255) / 256, 256, 0, stream>>>(w3, w3_hi, w3_lo);
    prep_wT<<<(HID * (NFC + HID) + 255) / 256, 256, 0, stream>>>(wf, wn, wfT, wnT);

    for (int f0 = 0; f0 < NFRAMES; f0 += CHUNK) {
        conv_fused<<<CHUNK, 320, 0, stream>>>(input, noise, w1, w2, a2h, a2l, f0);
        gemm_fc3<<<dim3(CHUNK / 64, NFC / 64), 128, 0, stream>>>(a2h, a2l, w3_hi, w3_lo, xs, f0);
    }

    mgu_kernel<<<NSEQ / 16, 256, 0, stream>>>(xs, wfT, wnT, w5, out);
}